// Round 7
// baseline (1640.312 us; speedup 1.0000x reference)
//
#include <hip/hip_runtime.h>

#define NN 100000
#define FD 128
#define ELLW 64
#define NRANGE 8                 // dst-range groups (== XCD count)
#define RSPAN (NN / NRANGE)      // 12500 nodes per range
#define CAP 32768                // pairs per (range, xcd) sub-bucket
#define CAPSH 15
#define BPG2 128                 // phase-B blocks per range

__device__ __forceinline__ unsigned pack_bf2(float lo, float hi) {
    unsigned a = __float_as_uint(lo), b = __float_as_uint(hi);
    a += 0x7FFF + ((a >> 16) & 1);
    b += 0x7FFF + ((b >> 16) & 1);
    return (a >> 16) | (b & 0xFFFF0000u);
}
__device__ __forceinline__ float bf_lo(unsigned v) { return __uint_as_float(v << 16); }
__device__ __forceinline__ float bf_hi(unsigned v) { return __uint_as_float(v & 0xFFFF0000u); }

// ---------------- phase A: bin edges into 64 (range, xcd) sub-buckets ----------------
// wave-aggregated append: one cursor atomic per wave per bucket; pair writes are
// dense at the bucket tail, and each sub-bucket is written by ONE xcd's blocks.
__global__ __launch_bounds__(256) void k_binA(const int* __restrict__ row,
                                              const int* __restrict__ col,
                                              uint2* __restrict__ pairs,
                                              int* __restrict__ cur, int E) {
    int i = blockIdx.x * 256 + threadIdx.x;
    int lane = threadIdx.x & 63;
    int x = blockIdx.x & (NRANGE - 1);
    bool valid = i < E;
    int dst = valid ? col[i] : 0;
    int src = valid ? row[i] : 0;
    int g = valid ? (dst / RSPAN) : NRANGE;   // NRANGE = no bucket
#pragma unroll
    for (int gg = 0; gg < NRANGE; ++gg) {
        unsigned long long m = __ballot(g == gg);
        if (!m) continue;
        int n = __popcll(m);
        int rank = __popcll(m & ((1ull << lane) - 1ull));
        int leader = __ffsll((long long)m) - 1;
        int base = 0;
        if (lane == leader) base = atomicAdd(&cur[gg * NRANGE + x], n);
        base = __shfl(base, leader);
        if (g == gg) {
            int k = base + rank;
            if (k < CAP) pairs[((gg * NRANGE + x) << CAPSH) + k] = make_uint2((unsigned)dst, (unsigned)src);
        }
    }
}

// ---------------- phase B: drain sub-buckets, build ELL (xcd-local) ----------------
__global__ __launch_bounds__(256) void k_binB(const uint2* __restrict__ pairs,
                                              const int* __restrict__ cur,
                                              int* __restrict__ cnt,
                                              int* __restrict__ ell) {
    int g = blockIdx.x & (NRANGE - 1);
    int b = blockIdx.x >> 3;
#pragma unroll 1
    for (int x = 0; x < NRANGE; ++x) {
        int len = cur[g * NRANGE + x];
        if (len > CAP) len = CAP;
        const uint2* seg = pairs + ((g * NRANGE + x) << CAPSH);
        for (int t = b * 256 + threadIdx.x; t < len; t += BPG2 * 256) {
            uint2 p = seg[t];
            int pos = atomicAdd(&cnt[p.x], 1);
            if (pos < ELLW) ell[(size_t)p.x * ELLW + pos] = (int)p.y;
        }
    }
}

__global__ __launch_bounds__(256) void k_dinv(const int* __restrict__ cnt,
                                              float* __restrict__ dinv) {
    int i = blockIdx.x * 256 + threadIdx.x;
    if (i < NN) dinv[i] = rsqrtf((float)(cnt[i] + 1));
}

// ---------------- GEMM-1: Hs[N,128](bf16) = dinv[i] * (X @ W1) ----------------
__global__ __launch_bounds__(256) void k_gemm(const float* __restrict__ X,
                                              const float* __restrict__ W,
                                              const float* __restrict__ dinv,
                                              unsigned* __restrict__ Hs) {
    __shared__ float Ws[FD * FD];
    __shared__ float Xs[32 * FD];
    const int tid = threadIdx.x;
    {
        const float4* W4 = (const float4*)W;
        float4* S4 = (float4*)Ws;
#pragma unroll
        for (int i = 0; i < 16; ++i) S4[tid + 256 * i] = W4[tid + 256 * i];
        const float4* X4 = (const float4*)(X + (size_t)blockIdx.x * 32 * FD);
        float4* XS4 = (float4*)Xs;
#pragma unroll
        for (int i = 0; i < 4; ++i) XS4[tid + 256 * i] = X4[tid + 256 * i];
    }
    __syncthreads();
    const int rg = tid >> 5, cg = tid & 31;
    float acc[4][4] = {};
#pragma unroll 4
    for (int k = 0; k < FD; ++k) {
        const float4 w = *(const float4*)&Ws[k * FD + cg * 4];
#pragma unroll
        for (int r = 0; r < 4; ++r) {
            const float xv = Xs[(rg * 4 + r) * FD + k];
            acc[r][0] = fmaf(xv, w.x, acc[r][0]);
            acc[r][1] = fmaf(xv, w.y, acc[r][1]);
            acc[r][2] = fmaf(xv, w.z, acc[r][2]);
            acc[r][3] = fmaf(xv, w.w, acc[r][3]);
        }
    }
    uint2* H2 = (uint2*)(Hs + (size_t)blockIdx.x * 32 * 64);
#pragma unroll
    for (int r = 0; r < 4; ++r) {
        float dv = dinv[blockIdx.x * 32 + rg * 4 + r];
        uint2 p;
        p.x = pack_bf2(dv * acc[r][0], dv * acc[r][1]);
        p.y = pack_bf2(dv * acc[r][2], dv * acc[r][3]);
        H2[(rg * 4 + r) * 32 + cg] = p;
    }
}

// ---------------- w2c = W2 @ Wc (128 floats); w2c[128] = dot(b2,Wc)+bc ----------------
__global__ __launch_bounds__(128) void k_w2c(const float* __restrict__ W2,
                                             const float* __restrict__ Wc,
                                             const float* __restrict__ b2,
                                             const float* __restrict__ bc,
                                             float* __restrict__ w2c) {
    int k = threadIdx.x;
    float v = 0.f;
    for (int j = 0; j < FD; ++j) v = fmaf(W2[k * FD + j], Wc[j], v);
    w2c[k] = v;
    if (k == 0) {
        float c0 = bc[0];
        for (int j = 0; j < FD; ++j) c0 = fmaf(b2[j], Wc[j], c0);
        w2c[FD] = c0;
    }
}

// ---------------- gather-1 + fused layer-2 projection ----------------
// 16 lanes per node; lane sub holds cols 8sub..8sub+7 (one uint4 of bf16x8).
__global__ __launch_bounds__(256) void k_gather1(const int* __restrict__ ell,
                                                 const int* __restrict__ cnt,
                                                 const float* __restrict__ dinv,
                                                 const unsigned* __restrict__ Hs,
                                                 const float* __restrict__ b1,
                                                 const float* __restrict__ w2c,
                                                 float* __restrict__ s) {
    int gid = blockIdx.x * 256 + threadIdx.x;
    int node = gid >> 4;
    int sub = threadIdx.x & 15;
    if (node >= NN) return;
    int c = cnt[node];
    int cl = (c < ELLW) ? c : ELLW;
    const uint4* H4 = (const uint4*)Hs;         // 16 uint4 per row
    uint4 u = H4[(size_t)node * 16 + sub];      // self-loop term
    float a0 = bf_lo(u.x), a1 = bf_hi(u.x), a2 = bf_lo(u.y), a3 = bf_hi(u.y);
    float a4 = bf_lo(u.z), a5 = bf_hi(u.z), a6 = bf_lo(u.w), a7 = bf_hi(u.w);
    const int* erow = ell + (size_t)node * ELLW;
    const int grpbase = threadIdx.x & 48;       // group base within wave
    for (int eb = 0; eb < cl; eb += 16) {
        int m = cl - eb; if (m > 16) m = 16;
        int idx = (eb + sub < cl) ? erow[eb + sub] : 0;   // 64B coalesced per group
        for (int j = 0; j < m; ++j) {
            int sv = __shfl(idx, grpbase + j);
            uint4 v = H4[(size_t)sv * 16 + sub];
            a0 += bf_lo(v.x); a1 += bf_hi(v.x);
            a2 += bf_lo(v.y); a3 += bf_hi(v.y);
            a4 += bf_lo(v.z); a5 += bf_hi(v.z);
            a6 += bf_lo(v.w); a7 += bf_hi(v.w);
        }
    }
    float dv = dinv[node];
    float4 bA = ((const float4*)b1)[sub * 2], bB = ((const float4*)b1)[sub * 2 + 1];
    float4 wA = ((const float4*)w2c)[sub * 2], wB = ((const float4*)w2c)[sub * 2 + 1];
    float p = fmaxf(fmaf(dv, a0, bA.x), 0.f) * wA.x;
    p = fmaf(fmaxf(fmaf(dv, a1, bA.y), 0.f), wA.y, p);
    p = fmaf(fmaxf(fmaf(dv, a2, bA.z), 0.f), wA.z, p);
    p = fmaf(fmaxf(fmaf(dv, a3, bA.w), 0.f), wA.w, p);
    p = fmaf(fmaxf(fmaf(dv, a4, bB.x), 0.f), wB.x, p);
    p = fmaf(fmaxf(fmaf(dv, a5, bB.y), 0.f), wB.y, p);
    p = fmaf(fmaxf(fmaf(dv, a6, bB.z), 0.f), wB.z, p);
    p = fmaf(fmaxf(fmaf(dv, a7, bB.w), 0.f), wB.w, p);
#pragma unroll
    for (int o = 1; o < 16; o <<= 1) p += __shfl_xor(p, o);
    if (sub == 0) s[node] = dv * p;
}

// ---------------- gather-2 (scalar) + sigmoid: 16 lanes per node ----------------
__global__ __launch_bounds__(256) void k_gather2(const int* __restrict__ ell,
                                                 const int* __restrict__ cnt,
                                                 const float* __restrict__ dinv,
                                                 const float* __restrict__ s,
                                                 const float* __restrict__ w2c,
                                                 float* __restrict__ out) {
    int gid = blockIdx.x * 256 + threadIdx.x;
    int node = gid >> 4;
    int sub = threadIdx.x & 15;
    if (node >= NN) return;
    int c = cnt[node];
    int cl = (c < ELLW) ? c : ELLW;
    const int* erow = ell + (size_t)node * ELLW;
    float acc = (sub == 0) ? s[node] : 0.f;
    for (int e = sub; e < cl; e += 16) acc += s[erow[e]];
#pragma unroll
    for (int o = 1; o < 16; o <<= 1) acc += __shfl_xor(acc, o);
    if (sub == 0) {
        float logit = fmaf(dinv[node], acc, w2c[FD]);
        out[node] = 1.0f / (1.0f + expf(-logit));
    }
}

extern "C" void kernel_launch(void* const* d_in, const int* in_sizes, int n_in,
                              void* d_out, int out_size, void* d_ws, size_t ws_size,
                              hipStream_t stream) {
    const float* x  = (const float*)d_in[0];
    const int*   ei = (const int*)d_in[1];
    const float* W1 = (const float*)d_in[2];
    const float* b1 = (const float*)d_in[3];
    const float* W2 = (const float*)d_in[4];
    const float* b2 = (const float*)d_in[5];
    const float* Wc = (const float*)d_in[6];
    const float* bc = (const float*)d_in[7];
    float* out = (float*)d_out;

    const int E = in_sizes[1] / 2;
    const int* row = ei;
    const int* col = ei + E;

    // workspace layout (16B-aligned throughout)
    float* dinv   = (float*)d_ws;                         // NN floats
    int* cnt      = (int*)(dinv + NN);                    // NN ints
    int* cur      = cnt + NN;                             // 64 ints (pad to 64)
    int* ell      = cur + 64;                             // NN*ELLW ints   (25.6 MB)
    uint2* pairs  = (uint2*)(ell + (size_t)NN * ELLW);    // 64*CAP uint2   (16.8 MB)
    unsigned* Hs  = (unsigned*)(pairs + 64 * CAP);        // NN*64 uints    (25.6 MB)
    float* sbuf   = (float*)(Hs + (size_t)NN * 64);       // NN floats
    float* w2c    = sbuf + NN;                            // 132 floats

    const int gemm_blocks = NN / 32;                      // 3125
    const int g16 = (NN * 16 + 255) / 256;                // 6250
    const int gn = (NN + 255) / 256;                      // 391
    const int ge = (E + 255) / 256;                       // 6250

    // binned ELL build: zero cnt+cursors, bin, drain
    hipMemsetAsync(cnt, 0, (NN + 64) * sizeof(int), stream);
    k_binA<<<ge, 256, 0, stream>>>(row, col, pairs, cur, E);
    k_binB<<<NRANGE * BPG2, 256, 0, stream>>>(pairs, cur, cnt, ell);
    k_dinv<<<gn, 256, 0, stream>>>(cnt, dinv);

    // projection vector for collapsed layer 2
    k_w2c<<<1, 128, 0, stream>>>(W2, Wc, b2, bc, w2c);

    // layer 1 GEMM (bf16 output, dinv folded)
    k_gemm<<<gemm_blocks, 256, 0, stream>>>(x, W1, dinv, Hs);

    // gather-1 fused with layer-2 projection -> per-node scalar s
    k_gather1<<<g16, 256, 0, stream>>>(ell, cnt, dinv, Hs, b1, w2c, sbuf);

    // gather-2 + sigmoid
    k_gather2<<<g16, 256, 0, stream>>>(ell, cnt, dinv, sbuf, w2c, out);
    (void)n_in; (void)out_size; (void)ws_size;
}

// Round 8
// 225.025 us; speedup vs baseline: 7.2895x; 7.2895x over previous
//
#include <hip/hip_runtime.h>

#define NN 100000
#define FD 128
#define ELLW 64
#define NRANGE 8                 // dst-range groups (== XCD count)
#define RSPAN (NN / NRANGE)      // 12500 nodes per range
#define BPG 256                  // blocks per range group

__device__ __forceinline__ unsigned pack_bf2(float lo, float hi) {
    unsigned a = __float_as_uint(lo), b = __float_as_uint(hi);
    a += 0x7FFF + ((a >> 16) & 1);
    b += 0x7FFF + ((b >> 16) & 1);
    return (a >> 16) | (b & 0xFFFF0000u);
}
__device__ __forceinline__ float bf_lo(unsigned v) { return __uint_as_float(v << 16); }
__device__ __forceinline__ float bf_hi(unsigned v) { return __uint_as_float(v & 0xFFFF0000u); }

// ---------------- fused ELL build (XCD-range-partitioned, nt streaming reads) ----------------
// group g = blockIdx & 7 owns dst in [g*RSPAN,(g+1)*RSPAN); consecutive blockIdx
// round-robin across the 8 XCDs, so each range's cnt/ell lines stay in ONE L2.
// col/row are read NON-TEMPORALLY so the 12.8MB stream doesn't evict the
// partially-filled dirty ELL lines (3.2MB/XCD) out of the 4MB L2 (R5: 79MB
// write amplification from exactly that eviction).
__global__ __launch_bounds__(256) void k_scatter_ell(const int* __restrict__ row,
                                                     const int* __restrict__ col,
                                                     int* __restrict__ cnt,
                                                     int* __restrict__ ell, int E) {
    int grp = blockIdx.x & (NRANGE - 1);
    int bid = blockIdx.x >> 3;
    int lo = grp * RSPAN, hi = lo + RSPAN;
    for (int i = bid * 256 + threadIdx.x; i < E; i += BPG * 256) {
        int c = __builtin_nontemporal_load(&col[i]);
        if (c >= lo && c < hi) {
            int r = __builtin_nontemporal_load(&row[i]);
            int pos = atomicAdd(&cnt[c], 1);
            if (pos < ELLW) ell[(size_t)c * ELLW + pos] = r;
        }
    }
}

// ---------------- GEMM-1: Hs[N,128](bf16) = rsqrt(cnt+1) * (X @ W1) ----------------
__global__ __launch_bounds__(256) void k_gemm(const float* __restrict__ X,
                                              const float* __restrict__ W,
                                              const int* __restrict__ cnt,
                                              unsigned* __restrict__ Hs) {
    __shared__ float Ws[FD * FD];
    __shared__ float Xs[32 * FD];
    const int tid = threadIdx.x;
    {
        const float4* W4 = (const float4*)W;
        float4* S4 = (float4*)Ws;
#pragma unroll
        for (int i = 0; i < 16; ++i) S4[tid + 256 * i] = W4[tid + 256 * i];
        const float4* X4 = (const float4*)(X + (size_t)blockIdx.x * 32 * FD);
        float4* XS4 = (float4*)Xs;
#pragma unroll
        for (int i = 0; i < 4; ++i) XS4[tid + 256 * i] = X4[tid + 256 * i];
    }
    __syncthreads();
    const int rg = tid >> 5, cg = tid & 31;
    float acc[4][4] = {};
#pragma unroll 4
    for (int k = 0; k < FD; ++k) {
        const float4 w = *(const float4*)&Ws[k * FD + cg * 4];
#pragma unroll
        for (int r = 0; r < 4; ++r) {
            const float xv = Xs[(rg * 4 + r) * FD + k];
            acc[r][0] = fmaf(xv, w.x, acc[r][0]);
            acc[r][1] = fmaf(xv, w.y, acc[r][1]);
            acc[r][2] = fmaf(xv, w.z, acc[r][2]);
            acc[r][3] = fmaf(xv, w.w, acc[r][3]);
        }
    }
    uint2* H2 = (uint2*)(Hs + (size_t)blockIdx.x * 32 * 64);
#pragma unroll
    for (int r = 0; r < 4; ++r) {
        float dv = rsqrtf((float)(cnt[blockIdx.x * 32 + rg * 4 + r] + 1));
        uint2 p;
        p.x = pack_bf2(dv * acc[r][0], dv * acc[r][1]);
        p.y = pack_bf2(dv * acc[r][2], dv * acc[r][3]);
        H2[(rg * 4 + r) * 32 + cg] = p;
    }
}

// ---------------- w2c = W2 @ Wc (128 floats); w2c[128] = dot(b2,Wc)+bc ----------------
__global__ __launch_bounds__(128) void k_w2c(const float* __restrict__ W2,
                                             const float* __restrict__ Wc,
                                             const float* __restrict__ b2,
                                             const float* __restrict__ bc,
                                             float* __restrict__ w2c) {
    int k = threadIdx.x;
    float v = 0.f;
    for (int j = 0; j < FD; ++j) v = fmaf(W2[k * FD + j], Wc[j], v);
    w2c[k] = v;
    if (k == 0) {
        float c0 = bc[0];
        for (int j = 0; j < FD; ++j) c0 = fmaf(b2[j], Wc[j], c0);
        w2c[FD] = c0;
    }
}

// ---------------- gather-1 + fused layer-2 projection ----------------
// 16 lanes per node; lane sub holds cols 8sub..8sub+7 (one uint4 of bf16x8).
// s[i] = dinv[i] * dot( relu(dinv[i]*(Hs[i]+sum_j Hs[j]) + b1), w2c )
__global__ __launch_bounds__(256) void k_gather1(const int* __restrict__ ell,
                                                 const int* __restrict__ cnt,
                                                 const unsigned* __restrict__ Hs,
                                                 const float* __restrict__ b1,
                                                 const float* __restrict__ w2c,
                                                 float* __restrict__ s) {
    int gid = blockIdx.x * 256 + threadIdx.x;
    int node = gid >> 4;
    int sub = threadIdx.x & 15;
    if (node >= NN) return;
    int c = cnt[node];
    int cl = (c < ELLW) ? c : ELLW;
    const uint4* H4 = (const uint4*)Hs;         // 16 uint4 per row
    uint4 u = H4[(size_t)node * 16 + sub];      // self-loop term
    float a0 = bf_lo(u.x), a1 = bf_hi(u.x), a2 = bf_lo(u.y), a3 = bf_hi(u.y);
    float a4 = bf_lo(u.z), a5 = bf_hi(u.z), a6 = bf_lo(u.w), a7 = bf_hi(u.w);
    const int* erow = ell + (size_t)node * ELLW;
    const int grpbase = threadIdx.x & 48;       // group base within wave
    for (int eb = 0; eb < cl; eb += 16) {
        int m = cl - eb; if (m > 16) m = 16;
        int idx = (eb + sub < cl) ? __builtin_nontemporal_load(&erow[eb + sub]) : 0;
        for (int j = 0; j < m; ++j) {
            int sv = __shfl(idx, grpbase + j);
            uint4 v = H4[(size_t)sv * 16 + sub];
            a0 += bf_lo(v.x); a1 += bf_hi(v.x);
            a2 += bf_lo(v.y); a3 += bf_hi(v.y);
            a4 += bf_lo(v.z); a5 += bf_hi(v.z);
            a6 += bf_lo(v.w); a7 += bf_hi(v.w);
        }
    }
    float dv = rsqrtf((float)(c + 1));
    float4 bA = ((const float4*)b1)[sub * 2], bB = ((const float4*)b1)[sub * 2 + 1];
    float4 wA = ((const float4*)w2c)[sub * 2], wB = ((const float4*)w2c)[sub * 2 + 1];
    float p = fmaxf(fmaf(dv, a0, bA.x), 0.f) * wA.x;
    p = fmaf(fmaxf(fmaf(dv, a1, bA.y), 0.f), wA.y, p);
    p = fmaf(fmaxf(fmaf(dv, a2, bA.z), 0.f), wA.z, p);
    p = fmaf(fmaxf(fmaf(dv, a3, bA.w), 0.f), wA.w, p);
    p = fmaf(fmaxf(fmaf(dv, a4, bB.x), 0.f), wB.x, p);
    p = fmaf(fmaxf(fmaf(dv, a5, bB.y), 0.f), wB.y, p);
    p = fmaf(fmaxf(fmaf(dv, a6, bB.z), 0.f), wB.z, p);
    p = fmaf(fmaxf(fmaf(dv, a7, bB.w), 0.f), wB.w, p);
#pragma unroll
    for (int o = 1; o < 16; o <<= 1) p += __shfl_xor(p, o);
    if (sub == 0) s[node] = dv * p;
}

// ---------------- gather-2 (scalar) + sigmoid: 16 lanes per node ----------------
__global__ __launch_bounds__(256) void k_gather2(const int* __restrict__ ell,
                                                 const int* __restrict__ cnt,
                                                 const float* __restrict__ s,
                                                 const float* __restrict__ w2c,
                                                 float* __restrict__ out) {
    int gid = blockIdx.x * 256 + threadIdx.x;
    int node = gid >> 4;
    int sub = threadIdx.x & 15;
    if (node >= NN) return;
    int c = cnt[node];
    int cl = (c < ELLW) ? c : ELLW;
    const int* erow = ell + (size_t)node * ELLW;
    float acc = (sub == 0) ? s[node] : 0.f;
    for (int e = sub; e < cl; e += 16) acc += s[__builtin_nontemporal_load(&erow[e])];
#pragma unroll
    for (int o = 1; o < 16; o <<= 1) acc += __shfl_xor(acc, o);
    if (sub == 0) {
        float logit = fmaf(rsqrtf((float)(c + 1)), acc, w2c[FD]);
        out[node] = 1.0f / (1.0f + expf(-logit));
    }
}

extern "C" void kernel_launch(void* const* d_in, const int* in_sizes, int n_in,
                              void* d_out, int out_size, void* d_ws, size_t ws_size,
                              hipStream_t stream) {
    const float* x  = (const float*)d_in[0];
    const int*   ei = (const int*)d_in[1];
    const float* W1 = (const float*)d_in[2];
    const float* b1 = (const float*)d_in[3];
    const float* W2 = (const float*)d_in[4];
    const float* b2 = (const float*)d_in[5];
    const float* Wc = (const float*)d_in[6];
    const float* bc = (const float*)d_in[7];
    float* out = (float*)d_out;

    const int E = in_sizes[1] / 2;
    const int* row = ei;
    const int* col = ei + E;

    // workspace layout (16B-aligned throughout)
    int* cnt      = (int*)d_ws;                           // NN ints
    int* ell      = cnt + NN;                             // NN*ELLW ints   (25.6 MB)
    unsigned* Hs  = (unsigned*)(ell + (size_t)NN * ELLW); // NN*64 uints    (25.6 MB)
    float* sbuf   = (float*)(Hs + (size_t)NN * 64);       // NN floats
    float* w2c    = sbuf + NN;                            // 132 floats

    const int gemm_blocks = NN / 32;                      // 3125
    const int g16 = (NN * 16 + 255) / 256;                // 6250
    const int gpart = NRANGE * BPG;                       // 2048 blocks

    // fused ELL build (counts + adjacency in one pass)
    hipMemsetAsync(cnt, 0, NN * sizeof(int), stream);
    k_scatter_ell<<<gpart, 256, 0, stream>>>(row, col, cnt, ell, E);

    // projection vector for collapsed layer 2
    k_w2c<<<1, 128, 0, stream>>>(W2, Wc, b2, bc, w2c);

    // layer 1 GEMM (bf16 output, dinv folded)
    k_gemm<<<gemm_blocks, 256, 0, stream>>>(x, W1, cnt, Hs);

    // gather-1 fused with layer-2 projection -> per-node scalar s
    k_gather1<<<g16, 256, 0, stream>>>(ell, cnt, Hs, b1, w2c, sbuf);

    // gather-2 + sigmoid
    k_gather2<<<g16, 256, 0, stream>>>(ell, cnt, sbuf, w2c, out);
    (void)n_in; (void)out_size; (void)ws_size;
}

// Round 10
// 187.891 us; speedup vs baseline: 8.7301x; 1.1976x over previous
//
#include <hip/hip_runtime.h>

#define NN 100000
#define FD 128
#define ELLW 64
#define NRANGE 8                 // dst-range groups (== XCD count)
#define RSPAN (NN / NRANGE)      // 12500 nodes per range
#define BPG 256                  // scatter blocks per range group
#define GEMM_BLOCKS 1563         // ceil(NN/64)
#define WT_S 136                 // padded LDS stride (bf16 elems) -> 272B, 16B-aligned

typedef float v4f __attribute__((ext_vector_type(4)));
typedef short v8s __attribute__((ext_vector_type(8)));
typedef int   v4i __attribute__((ext_vector_type(4)));

__device__ __forceinline__ unsigned pack_bf2(float lo, float hi) {
    unsigned a = __float_as_uint(lo), b = __float_as_uint(hi);
    a += 0x7FFF + ((a >> 16) & 1);
    b += 0x7FFF + ((b >> 16) & 1);
    return (a >> 16) | (b & 0xFFFF0000u);
}
__device__ __forceinline__ unsigned short bf1(float x) {
    unsigned u = __float_as_uint(x);
    u += 0x7FFF + ((u >> 16) & 1);
    return (unsigned short)(u >> 16);
}
__device__ __forceinline__ float bf_lo(unsigned v) { return __uint_as_float(v << 16); }
__device__ __forceinline__ float bf_hi(unsigned v) { return __uint_as_float(v & 0xFFFF0000u); }

// ---------------- ELL build (XCD-range-partitioned, int4-vectorized scan) ----------------
__global__ __launch_bounds__(256) void k_scatter_ell(const int* __restrict__ row,
                                                     const int* __restrict__ col,
                                                     int* __restrict__ cnt,
                                                     int* __restrict__ ell, int E) {
    int grp = blockIdx.x & (NRANGE - 1);
    int bid = blockIdx.x >> 3;
    int lo = grp * RSPAN, hi = lo + RSPAN;
    if ((E & 3) == 0) {
        const v4i* col4 = (const v4i*)col;
        const v4i* row4 = (const v4i*)row;
        int n4 = E >> 2;
        for (int i = bid * 256 + threadIdx.x; i < n4; i += BPG * 256) {
            v4i c = __builtin_nontemporal_load(&col4[i]);
            bool h0 = (c.x >= lo) & (c.x < hi);
            bool h1 = (c.y >= lo) & (c.y < hi);
            bool h2 = (c.z >= lo) & (c.z < hi);
            bool h3 = (c.w >= lo) & (c.w < hi);
            if (h0 | h1 | h2 | h3) {
                v4i r = __builtin_nontemporal_load(&row4[i]);
                if (h0) { int p = atomicAdd(&cnt[c.x], 1); if (p < ELLW) ell[(size_t)c.x * ELLW + p] = r.x; }
                if (h1) { int p = atomicAdd(&cnt[c.y], 1); if (p < ELLW) ell[(size_t)c.y * ELLW + p] = r.y; }
                if (h2) { int p = atomicAdd(&cnt[c.z], 1); if (p < ELLW) ell[(size_t)c.z * ELLW + p] = r.z; }
                if (h3) { int p = atomicAdd(&cnt[c.w], 1); if (p < ELLW) ell[(size_t)c.w * ELLW + p] = r.w; }
            }
        }
    } else {
        for (int i = bid * 256 + threadIdx.x; i < E; i += BPG * 256) {
            int c = __builtin_nontemporal_load(&col[i]);
            if (c >= lo && c < hi) {
                int r = __builtin_nontemporal_load(&row[i]);
                int pos = atomicAdd(&cnt[c], 1);
                if (pos < ELLW) ell[(size_t)c * ELLW + pos] = r;
            }
        }
    }
}

// ---------------- fused: dinv + MFMA GEMM (Hs = bf16(X@W1), raw) + w2c ----------------
// blocks [0,GEMM_BLOCKS): 64 rows each via mfma_f32_16x16x32_bf16.
// block GEMM_BLOCKS: w2c = W2@Wc, w2c[FD] = dot(b2,Wc)+bc.
// every block also computes 64 entries of dinv = rsqrt(cnt+1) (cnt final: runs after scatter).
__global__ __launch_bounds__(256) void k_gemm_fused(const float* __restrict__ X,
                                                    const float* __restrict__ W1,
                                                    const float* __restrict__ W2,
                                                    const float* __restrict__ Wc,
                                                    const float* __restrict__ b2,
                                                    const float* __restrict__ bc,
                                                    const int* __restrict__ cnt,
                                                    float* __restrict__ dinv,
                                                    unsigned* __restrict__ Hs,
                                                    float* __restrict__ w2c) {
    const int tid = threadIdx.x;
    // side duty: dinv slice
    {
        int nb = blockIdx.x * 64 + tid;
        if (tid < 64 && nb < NN) dinv[nb] = rsqrtf((float)(cnt[nb] + 1));
    }
    if (blockIdx.x == GEMM_BLOCKS) {
        int k = tid;
        if (k < FD) {
            float v = 0.f;
            for (int j = 0; j < FD; ++j) v = fmaf(W2[k * FD + j], Wc[j], v);
            w2c[k] = v;
            if (k == 0) {
                float c0 = bc[0];
                for (int j = 0; j < FD; ++j) c0 = fmaf(b2[j], Wc[j], c0);
                w2c[FD] = c0;
            }
        }
        return;
    }

    __shared__ short lds[FD * WT_S + 64 * WT_S];   // Wt [128][136] + Xs/Os [64][136] = 52KB
    short* Wt = lds;
    short* Xs = lds + FD * WT_S;
    const int gr0 = blockIdx.x * 64;

    // stage Wt[n][k] = bf16(W1[k][n]); thread: n = tid&127, ks = tid>>7
    {
        int n = tid & 127, ks = tid >> 7;
        for (int it = 0; it < 16; ++it) {
            int k0 = it * 8 + ks * 4;
            float f0 = W1[(k0 + 0) * FD + n];
            float f1 = W1[(k0 + 1) * FD + n];
            float f2 = W1[(k0 + 2) * FD + n];
            float f3 = W1[(k0 + 3) * FD + n];
            *(uint2*)&Wt[n * WT_S + k0] = make_uint2(pack_bf2(f0, f1), pack_bf2(f2, f3));
        }
    }
    // stage Xs[r][c] = bf16(X[gr0+r][c]) (zeros past NN)
    for (int it = 0; it < 8; ++it) {
        int f = tid + 256 * it;            // float4 index within 64x128 tile
        int r = f >> 5, c4 = (f & 31) * 4;
        float4 xv = make_float4(0.f, 0.f, 0.f, 0.f);
        if (gr0 + r < NN) xv = ((const float4*)X)[(size_t)(gr0 + r) * 32 + (f & 31)];
        *(uint2*)&Xs[r * WT_S + c4] = make_uint2(pack_bf2(xv.x, xv.y), pack_bf2(xv.z, xv.w));
    }
    __syncthreads();

    const int wv = tid >> 6, l = tid & 63;
    const int lrow = l & 15, lk = (l >> 4) * 8;
    v4f acc[8];
#pragma unroll
    for (int n = 0; n < 8; ++n) acc[n] = (v4f){0.f, 0.f, 0.f, 0.f};
#pragma unroll
    for (int kk = 0; kk < 4; ++kk) {
        v8s a = *(const v8s*)&Xs[(wv * 16 + lrow) * WT_S + kk * 32 + lk];
#pragma unroll
        for (int n = 0; n < 8; ++n) {
            v8s b = *(const v8s*)&Wt[(n * 16 + lrow) * WT_S + kk * 32 + lk];
            acc[n] = __builtin_amdgcn_mfma_f32_16x16x32_bf16(a, b, acc[n], 0, 0, 0);
        }
    }
    __syncthreads();                        // done reading Xs; reuse as Os
    short* Os = Xs;
#pragma unroll
    for (int n = 0; n < 8; ++n)
#pragma unroll
        for (int r = 0; r < 4; ++r) {
            int orow = wv * 16 + (l >> 4) * 4 + r;
            Os[orow * WT_S + n * 16 + lrow] = (short)bf1(acc[n][r]);
        }
    __syncthreads();
    // coalesced bf16x2 store
    for (int it = 0; it < 16; ++it) {
        int idx = tid + 256 * it;          // uint index within 64x64
        int r = idx >> 6, cu = idx & 63;
        if (gr0 + r < NN)
            Hs[(size_t)(gr0 + r) * 64 + cu] = *(const unsigned*)&Os[r * WT_S + cu * 2];
    }
}

// ---------------- gather-1 + fused layer-2 projection ----------------
// 16 lanes per node; lane sub holds cols 8sub..8sub+7 (uint4 of bf16x8).
// A = dinv_i*h_i + sum_src dinv_src*h_src ; h1 = relu(dinv_i*A + b1);
// s_i = dinv_i * dot(h1, w2c)
__global__ __launch_bounds__(256) void k_gather1(const int* __restrict__ ell,
                                                 const int* __restrict__ cnt,
                                                 const float* __restrict__ dinv,
                                                 const unsigned* __restrict__ Hs,
                                                 const float* __restrict__ b1,
                                                 const float* __restrict__ w2c,
                                                 float* __restrict__ s) {
    int gid = blockIdx.x * 256 + threadIdx.x;
    int node = gid >> 4;
    int sub = threadIdx.x & 15;
    if (node >= NN) return;
    int c = cnt[node];
    int cl = (c < ELLW) ? c : ELLW;
    float dv = dinv[node];
    const uint4* H4 = (const uint4*)Hs;
    uint4 u = H4[(size_t)node * 16 + sub];
    float a0 = dv * bf_lo(u.x), a1 = dv * bf_hi(u.x), a2 = dv * bf_lo(u.y), a3 = dv * bf_hi(u.y);
    float a4 = dv * bf_lo(u.z), a5 = dv * bf_hi(u.z), a6 = dv * bf_lo(u.w), a7 = dv * bf_hi(u.w);
    const int* erow = ell + (size_t)node * ELLW;
    const int grpbase = threadIdx.x & 48;
    for (int eb = 0; eb < cl; eb += 16) {
        int m = cl - eb; if (m > 16) m = 16;
        int idx = (eb + sub < cl) ? __builtin_nontemporal_load(&erow[eb + sub]) : 0;
        for (int j = 0; j < m; ++j) {
            int sv = __shfl(idx, grpbase + j);
            float dvs = dinv[sv];
            uint4 v = H4[(size_t)sv * 16 + sub];
            a0 = fmaf(dvs, bf_lo(v.x), a0); a1 = fmaf(dvs, bf_hi(v.x), a1);
            a2 = fmaf(dvs, bf_lo(v.y), a2); a3 = fmaf(dvs, bf_hi(v.y), a3);
            a4 = fmaf(dvs, bf_lo(v.z), a4); a5 = fmaf(dvs, bf_hi(v.z), a5);
            a6 = fmaf(dvs, bf_lo(v.w), a6); a7 = fmaf(dvs, bf_hi(v.w), a7);
        }
    }
    float4 bA = ((const float4*)b1)[sub * 2], bB = ((const float4*)b1)[sub * 2 + 1];
    float4 wA = ((const float4*)w2c)[sub * 2], wB = ((const float4*)w2c)[sub * 2 + 1];
    float p = fmaxf(fmaf(dv, a0, bA.x), 0.f) * wA.x;
    p = fmaf(fmaxf(fmaf(dv, a1, bA.y), 0.f), wA.y, p);
    p = fmaf(fmaxf(fmaf(dv, a2, bA.z), 0.f), wA.z, p);
    p = fmaf(fmaxf(fmaf(dv, a3, bA.w), 0.f), wA.w, p);
    p = fmaf(fmaxf(fmaf(dv, a4, bB.x), 0.f), wB.x, p);
    p = fmaf(fmaxf(fmaf(dv, a5, bB.y), 0.f), wB.y, p);
    p = fmaf(fmaxf(fmaf(dv, a6, bB.z), 0.f), wB.z, p);
    p = fmaf(fmaxf(fmaf(dv, a7, bB.w), 0.f), wB.w, p);
#pragma unroll
    for (int o = 1; o < 16; o <<= 1) p += __shfl_xor(p, o);
    if (sub == 0) s[node] = dv * p;
}

// ---------------- gather-2 (scalar) + sigmoid: 16 lanes per node ----------------
__global__ __launch_bounds__(256) void k_gather2(const int* __restrict__ ell,
                                                 const int* __restrict__ cnt,
                                                 const float* __restrict__ s,
                                                 const float* __restrict__ w2c,
                                                 float* __restrict__ out) {
    int gid = blockIdx.x * 256 + threadIdx.x;
    int node = gid >> 4;
    int sub = threadIdx.x & 15;
    if (node >= NN) return;
    int c = cnt[node];
    int cl = (c < ELLW) ? c : ELLW;
    const int* erow = ell + (size_t)node * ELLW;
    float acc = (sub == 0) ? s[node] : 0.f;
    for (int e = sub; e < cl; e += 16) acc += s[__builtin_nontemporal_load(&erow[e])];
#pragma unroll
    for (int o = 1; o < 16; o <<= 1) acc += __shfl_xor(acc, o);
    if (sub == 0) {
        float logit = fmaf(rsqrtf((float)(c + 1)), acc, w2c[FD]);
        out[node] = 1.0f / (1.0f + expf(-logit));
    }
}

extern "C" void kernel_launch(void* const* d_in, const int* in_sizes, int n_in,
                              void* d_out, int out_size, void* d_ws, size_t ws_size,
                              hipStream_t stream) {
    const float* x  = (const float*)d_in[0];
    const int*   ei = (const int*)d_in[1];
    const float* W1 = (const float*)d_in[2];
    const float* b1 = (const float*)d_in[3];
    const float* W2 = (const float*)d_in[4];
    const float* b2 = (const float*)d_in[5];
    const float* Wc = (const float*)d_in[6];
    const float* bc = (const float*)d_in[7];
    float* out = (float*)d_out;

    const int E = in_sizes[1] / 2;
    const int* row = ei;
    const int* col = ei + E;

    // workspace layout (16B-aligned: NN*4 = 400000 = 16*25000)
    int* cnt      = (int*)d_ws;                           // NN ints
    float* dinv   = (float*)(cnt + NN);                   // NN floats
    int* ell      = (int*)(dinv + NN);                    // NN*ELLW ints  (25.6 MB)
    unsigned* Hs  = (unsigned*)(ell + (size_t)NN * ELLW); // NN*64 uints   (25.6 MB)
    float* sbuf   = (float*)(Hs + (size_t)NN * 64);       // NN floats
    float* w2c    = sbuf + NN;                            // 132 floats

    const int g16 = (NN * 16 + 255) / 256;                // 6250
    const int gpart = NRANGE * BPG;                       // 2048

    hipMemsetAsync(cnt, 0, NN * sizeof(int), stream);
    k_scatter_ell<<<gpart, 256, 0, stream>>>(row, col, cnt, ell, E);
    k_gemm_fused<<<GEMM_BLOCKS + 1, 256, 0, stream>>>(x, W1, W2, Wc, b2, bc, cnt, dinv, Hs, w2c);
    k_gather1<<<g16, 256, 0, stream>>>(ell, cnt, dinv, Hs, b1, w2c, sbuf);
    k_gather2<<<g16, 256, 0, stream>>>(ell, cnt, sbuf, w2c, out);
    (void)n_in; (void)out_size; (void)ws_size;
}